// Round 1
// baseline (295.503 us; speedup 1.0000x reference)
//
#include <hip/hip_runtime.h>

typedef __bf16 bf16;
typedef __bf16 bf16x8 __attribute__((ext_vector_type(8)));
typedef float floatx4 __attribute__((ext_vector_type(4)));

#define EPS 1.1920929e-07f

__device__ __forceinline__ floatx4 mfma16(bf16x8 a, bf16x8 b, floatx4 c) {
  return __builtin_amdgcn_mfma_f32_16x16x32_bf16(a, b, c, 0, 0, 0);
}

// ---------------- prep kernels ----------------
__global__ void cast_x_kernel(const float* __restrict__ x, bf16* __restrict__ xb, int n) {
  int i = blockIdx.x * blockDim.x + threadIdx.x;
  if (i < n) xb[i] = (bf16)x[i];
}

// Wqkv_t[n][k] (n<1024: Wq col n; n<1280: Wk col n-1024; else Wv col n-1280), bf16
__global__ void pack_wqkv_kernel(const float* __restrict__ Wq, const float* __restrict__ Wk,
                                 const float* __restrict__ Wv, bf16* __restrict__ out) {
  __shared__ float tile[32][33];
  int n0 = blockIdx.x * 32, k0 = blockIdx.y * 32;
  int tx = threadIdx.x & 31, ty = threadIdx.x >> 5;
#pragma unroll
  for (int i = 0; i < 4; i++) {
    int k = k0 + ty + i * 8, n = n0 + tx;
    float v;
    if (n < 1024)      v = Wq[(size_t)k * 1024 + n];
    else if (n < 1280) v = Wk[(size_t)k * 256 + (n - 1024)];
    else               v = Wv[(size_t)k * 256 + (n - 1280)];
    tile[ty + i * 8][tx] = v;
  }
  __syncthreads();
#pragma unroll
  for (int i = 0; i < 4; i++) {
    int n = n0 + ty + i * 8, k = k0 + tx;
    out[(size_t)n * 1024 + k] = (bf16)tile[tx][ty + i * 8];
  }
}

__global__ void trans_wproj_kernel(const float* __restrict__ W, bf16* __restrict__ out) {
  __shared__ float tile[32][33];
  int n0 = blockIdx.x * 32, k0 = blockIdx.y * 32;
  int tx = threadIdx.x & 31, ty = threadIdx.x >> 5;
#pragma unroll
  for (int i = 0; i < 4; i++)
    tile[ty + i * 8][tx] = W[(size_t)(k0 + ty + i * 8) * 1024 + n0 + tx];
  __syncthreads();
#pragma unroll
  for (int i = 0; i < 4; i++)
    out[(size_t)(n0 + ty + i * 8) * 1024 + k0 + tx] = (bf16)tile[tx][ty + i * 8];
}

// ---------------- GEMM: C[M][N] = A[M][K] * Bt[N][K]^T, bf16 in, fp32 acc ----------------
template <bool OUT_BF16>
__global__ __launch_bounds__(256) void gemm_kernel(const bf16* __restrict__ A,
                                                   const bf16* __restrict__ Bt,
                                                   void* __restrict__ Cout,
                                                   int M, int N, int K) {
  __shared__ bf16 As[128 * 40];
  __shared__ bf16 Bs[128 * 40];
  const int tid = threadIdx.x;
  const int m0 = blockIdx.y * 128, n0 = blockIdx.x * 128;
  const int w = tid >> 6, lane = tid & 63;
  const int q = lane >> 4, r0 = lane & 15;
  const int wr2 = w >> 1, wc2 = w & 1;
  const int srow = tid >> 2;
  const int scol = (tid & 3) * 8;

  floatx4 acc[4][4];
#pragma unroll
  for (int i = 0; i < 4; i++)
#pragma unroll
    for (int j = 0; j < 4; j++) acc[i][j] = (floatx4){0.f, 0.f, 0.f, 0.f};

  for (int k0 = 0; k0 < K; k0 += 32) {
    __syncthreads();
#pragma unroll
    for (int i = 0; i < 2; i++) {
      int r = srow + i * 64;
      *(uint4*)&As[r * 40 + scol] = *(const uint4*)(A + (size_t)(m0 + r) * K + k0 + scol);
      *(uint4*)&Bs[r * 40 + scol] = *(const uint4*)(Bt + (size_t)(n0 + r) * K + k0 + scol);
    }
    __syncthreads();
    bf16x8 af[4], bfr[4];
#pragma unroll
    for (int mt = 0; mt < 4; mt++) af[mt] = *(const bf16x8*)&As[(wr2 * 64 + mt * 16 + r0) * 40 + q * 8];
#pragma unroll
    for (int nt = 0; nt < 4; nt++) bfr[nt] = *(const bf16x8*)&Bs[(wc2 * 64 + nt * 16 + r0) * 40 + q * 8];
#pragma unroll
    for (int mt = 0; mt < 4; mt++)
#pragma unroll
      for (int nt = 0; nt < 4; nt++)
        acc[mt][nt] = mfma16(af[mt], bfr[nt], acc[mt][nt]);
  }
#pragma unroll
  for (int mt = 0; mt < 4; mt++)
#pragma unroll
    for (int nt = 0; nt < 4; nt++)
#pragma unroll
      for (int r = 0; r < 4; r++) {
        int row = m0 + wr2 * 64 + mt * 16 + q * 4 + r;
        int col = n0 + wc2 * 64 + nt * 16 + r0;
        float v = acc[mt][nt][r];
        if (OUT_BF16) ((bf16*)Cout)[(size_t)row * N + col] = (bf16)v;
        else          ((float*)Cout)[(size_t)row * N + col] = v;
      }
}

// ---------------- postproc: gate+ve add, RoPE, RMS, layout for attention ----------------
__global__ void postproc_kernel(const bf16* __restrict__ qkv, const float* __restrict__ x,
                                const float* __restrict__ ve, const float* __restrict__ cosb,
                                const float* __restrict__ sinb, const float* __restrict__ wgate,
                                bf16* __restrict__ Qb, bf16* __restrict__ Kb, bf16* __restrict__ Vt) {
  int t = blockIdx.x;
  int b = t >> 11, s = t & 2047;
  int lane = threadIdx.x;

  // gate = 2*sigmoid(x[:,:128] @ Wgate)  (Wgate: [128][4] row-major)
  float g[4];
  const float* xrow = x + (size_t)t * 1024;
  float x0 = xrow[lane], x1 = xrow[64 + lane];
#pragma unroll
  for (int kv = 0; kv < 4; kv++)
    g[kv] = x0 * wgate[lane * 4 + kv] + x1 * wgate[(64 + lane) * 4 + kv];
#pragma unroll
  for (int kv = 0; kv < 4; kv++) {
    float v = g[kv];
    for (int m = 1; m < 64; m <<= 1) v += __shfl_xor(v, m, 64);
    g[kv] = 2.f / (1.f + __expf(-v));
  }

  int d = lane & 31;
  float c = cosb[s * 32 + d], sn = sinb[s * 32 + d];
  float sgn = (lane < 32) ? sn : -sn;
  const bf16* qrow = qkv + (size_t)t * 1536;

  // q heads: rope -> rms -> *0.125 (score scale folded in)
  for (int h = 0; h < 16; h++) {
    float v = (float)qrow[h * 64 + lane];
    float p = __shfl_xor(v, 32, 64);
    float rv = v * c + p * sgn;
    float ss = rv * rv;
    for (int m = 1; m < 64; m <<= 1) ss += __shfl_xor(ss, m, 64);
    float outq = rv * rsqrtf(ss * (1.f / 64.f) + EPS) * 0.125f;
    Qb[(((size_t)b * 16 + h) * 2048 + s) * 64 + lane] = (bf16)outq;
  }
  // k heads + v (v gets gate*ve, no rope/rms; stored transposed [d][s])
  for (int kv = 0; kv < 4; kv++) {
    float v = (float)qrow[1024 + kv * 64 + lane];
    float p = __shfl_xor(v, 32, 64);
    float rv = v * c + p * sgn;
    float ss = rv * rv;
    for (int m = 1; m < 64; m <<= 1) ss += __shfl_xor(ss, m, 64);
    float outk = rv * rsqrtf(ss * (1.f / 64.f) + EPS);
    Kb[(((size_t)b * 4 + kv) * 2048 + s) * 64 + lane] = (bf16)outk;
    float vv = (float)qrow[1280 + kv * 64 + lane] + g[kv] * ve[(size_t)t * 256 + kv * 64 + lane];
    Vt[(((size_t)b * 4 + kv) * 64 + lane) * 2048 + s] = (bf16)vv;
  }
}

// ---------------- flash attention: 4 waves/block, 16 queries/wave, 32-key tiles ----------------
__global__ __launch_bounds__(256) void attn_kernel(const bf16* __restrict__ Qb,
                                                   const bf16* __restrict__ Kb,
                                                   const bf16* __restrict__ Vt,
                                                   const int* __restrict__ wlp,
                                                   const int* __restrict__ wrp,
                                                   bf16* __restrict__ Yb) {
  __shared__ bf16 Ps[4 * 16 * 40];
  const int wl = wlp[0];
  const int wrc = min(wrp[0], 0);  // j<=i+wr && j<=i  ==>  j <= i+min(wr,0)
  const int blk = blockIdx.x;
  const int qc = blk & 31;
  const int bh = blk >> 5;
  const int b = bh >> 4, h = bh & 15, kvh = (bh & 15) >> 2;
  const int w = threadIdx.x >> 6, lane = threadIdx.x & 63;
  const int q = lane >> 4, r0 = lane & 15;
  const int q0 = qc * 64 + w * 16;

  const bf16* qbase = Qb + (((size_t)b * 16 + h) * 2048 + q0 + r0) * 64;
  bf16x8 aq0 = *(const bf16x8*)(qbase + q * 8);
  bf16x8 aq1 = *(const bf16x8*)(qbase + 32 + q * 8);

  floatx4 Oacc[4];
#pragma unroll
  for (int nt = 0; nt < 4; nt++) Oacc[nt] = (floatx4){0.f, 0.f, 0.f, 0.f};
  float mrow[4], lrow[4];
#pragma unroll
  for (int r = 0; r < 4; r++) { mrow[r] = -1e30f; lrow[r] = 0.f; }

  int jlo = max(0, q0 - wl) & ~31;
  int jhi = q0 + 15 + wrc;

  const bf16* kbase = Kb + ((size_t)b * 4 + kvh) * 2048 * 64;
  const bf16* vbase = Vt + ((size_t)b * 4 + kvh) * 64 * 2048;
  bf16* psw = Ps + w * 640;

  for (int j0 = jlo; j0 <= jhi; j0 += 32) {
    bf16x8 kf00 = *(const bf16x8*)(kbase + (size_t)(j0 + r0) * 64 + q * 8);
    bf16x8 kf01 = *(const bf16x8*)(kbase + (size_t)(j0 + r0) * 64 + 32 + q * 8);
    bf16x8 kf10 = *(const bf16x8*)(kbase + (size_t)(j0 + 16 + r0) * 64 + q * 8);
    bf16x8 kf11 = *(const bf16x8*)(kbase + (size_t)(j0 + 16 + r0) * 64 + 32 + q * 8);
    floatx4 s0 = (floatx4){0.f, 0.f, 0.f, 0.f};
    floatx4 s1 = (floatx4){0.f, 0.f, 0.f, 0.f};
    s0 = mfma16(aq0, kf00, s0);
    s0 = mfma16(aq1, kf01, s0);
    s1 = mfma16(aq0, kf10, s1);
    s1 = mfma16(aq1, kf11, s1);

    float p0[4], p1[4];
#pragma unroll
    for (int r = 0; r < 4; r++) {
      int i = q0 + q * 4 + r;
      int ja = j0 + r0, jb = j0 + 16 + r0;
      bool va = (ja <= i + wrc) && (ja >= i - wl);
      bool vb = (jb <= i + wrc) && (jb >= i - wl);
      float sva = va ? s0[r] : -1e30f;
      float svb = vb ? s1[r] : -1e30f;
      float mt = fmaxf(sva, svb);
      mt = fmaxf(mt, __shfl_xor(mt, 1, 64));
      mt = fmaxf(mt, __shfl_xor(mt, 2, 64));
      mt = fmaxf(mt, __shfl_xor(mt, 4, 64));
      mt = fmaxf(mt, __shfl_xor(mt, 8, 64));
      float mnew = fmaxf(mrow[r], mt);
      float alpha = __expf(mrow[r] - mnew);
      float ea = va ? __expf(sva - mnew) : 0.f;
      float eb = vb ? __expf(svb - mnew) : 0.f;
      p0[r] = ea; p1[r] = eb;
      float rs = ea + eb;
      rs += __shfl_xor(rs, 1, 64);
      rs += __shfl_xor(rs, 2, 64);
      rs += __shfl_xor(rs, 4, 64);
      rs += __shfl_xor(rs, 8, 64);
      lrow[r] = lrow[r] * alpha + rs;
      mrow[r] = mnew;
#pragma unroll
      for (int nt = 0; nt < 4; nt++) Oacc[nt][r] *= alpha;
    }

    // P (C-layout) -> LDS -> A-layout bf16
#pragma unroll
    for (int r = 0; r < 4; r++) {
      psw[(q * 4 + r) * 40 + r0] = (bf16)p0[r];
      psw[(q * 4 + r) * 40 + 16 + r0] = (bf16)p1[r];
    }
    asm volatile("s_waitcnt lgkmcnt(0)" ::: "memory");
    bf16x8 pa = *(const bf16x8*)(psw + r0 * 40 + q * 8);
#pragma unroll
    for (int nt = 0; nt < 4; nt++) {
      bf16x8 vf = *(const bf16x8*)(vbase + (size_t)(nt * 16 + r0) * 2048 + j0 + q * 8);
      Oacc[nt] = mfma16(pa, vf, Oacc[nt]);
    }
  }

  float inv[4];
#pragma unroll
  for (int r = 0; r < 4; r++) inv[r] = lrow[r] > 0.f ? 1.f / lrow[r] : 0.f;
#pragma unroll
  for (int nt = 0; nt < 4; nt++)
#pragma unroll
    for (int r = 0; r < 4; r++) {
      int i = q0 + q * 4 + r;
      Yb[((size_t)b * 2048 + i) * 1024 + h * 64 + nt * 16 + r0] = (bf16)(Oacc[nt][r] * inv[r]);
    }
}

// ---------------- launch ----------------
extern "C" void kernel_launch(void* const* d_in, const int* in_sizes, int n_in,
                              void* d_out, int out_size, void* d_ws, size_t ws_size,
                              hipStream_t stream) {
  const float* x     = (const float*)d_in[0];
  const float* ve    = (const float*)d_in[1];
  const float* cosb  = (const float*)d_in[2];
  const float* sinb  = (const float*)d_in[3];
  const float* Wq    = (const float*)d_in[4];
  const float* Wk    = (const float*)d_in[5];
  const float* Wv    = (const float*)d_in[6];
  const float* Wproj = (const float*)d_in[7];
  const float* Wgate = (const float*)d_in[8];
  const int* wl      = (const int*)d_in[9];
  const int* wr      = (const int*)d_in[10];

  char* ws = (char*)d_ws;
  bf16* Xb      = (bf16*)(ws);                 //  8,388,608 B: x bf16 [4096][1024]
  bf16* Wqkv_t  = (bf16*)(ws + 8388608);       //  3,145,728 B: [1536][1024]
  bf16* Wproj_t = (bf16*)(ws + 11534336);      //  2,097,152 B: [1024][1024]
  bf16* qkvb    = (bf16*)(ws + 13631488);      // 12,582,912 B: [4096][1536]
  bf16* Qb      = (bf16*)(ws + 26214400);      //  8,388,608 B: [2][16][2048][64]
  bf16* Kb      = (bf16*)(ws + 34603008);      //  2,097,152 B: [2][4][2048][64]
  bf16* Vt      = (bf16*)(ws + 36700160);      //  2,097,152 B: [2][4][64][2048]
  bf16* Yb      = (bf16*)(ws + 38797312);      //  8,388,608 B: [4096][1024]  (total 47,185,920)

  cast_x_kernel<<<4194304 / 256, 256, 0, stream>>>(x, Xb, 4194304);
  pack_wqkv_kernel<<<dim3(48, 32), 256, 0, stream>>>(Wq, Wk, Wv, Wqkv_t);
  trans_wproj_kernel<<<dim3(32, 32), 256, 0, stream>>>(Wproj, Wproj_t);
  gemm_kernel<true><<<dim3(12, 32), 256, 0, stream>>>(Xb, Wqkv_t, qkvb, 4096, 1536, 1024);
  postproc_kernel<<<4096, 64, 0, stream>>>(qkvb, x, ve, cosb, sinb, Wgate, Qb, Kb, Vt);
  attn_kernel<<<1024, 256, 0, stream>>>(Qb, Kb, Vt, wl, wr, Yb);
  gemm_kernel<false><<<dim3(8, 32), 256, 0, stream>>>(Yb, Wproj_t, d_out, 4096, 1024, 1024);
}

// Round 2
// 290.963 us; speedup vs baseline: 1.0156x; 1.0156x over previous
//
#include <hip/hip_runtime.h>

typedef __bf16 bf16;
typedef __bf16 bf16x4 __attribute__((ext_vector_type(4)));
typedef __bf16 bf16x8 __attribute__((ext_vector_type(8)));
typedef float floatx4 __attribute__((ext_vector_type(4)));

#define EPS 1.1920929e-07f
// q scale = D^-0.5 * log2(e) folded together (D=64 -> 0.125)
#define QSCALE (0.125f * 1.44269504088896f)
// fixed softmax shift: |q_eff . k| <= ||q_eff||*||k|| = (8*QSCALE)*8 = 11.5416
#define SHIFT_C 11.5416f

__device__ __forceinline__ floatx4 mfma16(bf16x8 a, bf16x8 b, floatx4 c) {
  return __builtin_amdgcn_mfma_f32_16x16x32_bf16(a, b, c, 0, 0, 0);
}

// ---------------- prep kernels ----------------
__global__ void cast_x_kernel(const float* __restrict__ x, bf16* __restrict__ xb) {
  int i = (blockIdx.x * blockDim.x + threadIdx.x) * 4;
  float4 v = *(const float4*)(x + i);
  bf16x4 o = {(bf16)v.x, (bf16)v.y, (bf16)v.z, (bf16)v.w};
  *(bf16x4*)(xb + i) = o;
}

// Wqkv_t[n][k] (n<1024: Wq col n; n<1280: Wk col n-1024; else Wv col n-1280), bf16
__global__ void pack_wqkv_kernel(const float* __restrict__ Wq, const float* __restrict__ Wk,
                                 const float* __restrict__ Wv, bf16* __restrict__ out) {
  __shared__ float tile[32][33];
  int n0 = blockIdx.x * 32, k0 = blockIdx.y * 32;
  int tx = threadIdx.x & 31, ty = threadIdx.x >> 5;
#pragma unroll
  for (int i = 0; i < 4; i++) {
    int k = k0 + ty + i * 8, n = n0 + tx;
    float v;
    if (n < 1024)      v = Wq[(size_t)k * 1024 + n];
    else if (n < 1280) v = Wk[(size_t)k * 256 + (n - 1024)];
    else               v = Wv[(size_t)k * 256 + (n - 1280)];
    tile[ty + i * 8][tx] = v;
  }
  __syncthreads();
#pragma unroll
  for (int i = 0; i < 4; i++) {
    int n = n0 + ty + i * 8, k = k0 + tx;
    out[(size_t)n * 1024 + k] = (bf16)tile[tx][ty + i * 8];
  }
}

__global__ void trans_wproj_kernel(const float* __restrict__ W, bf16* __restrict__ out) {
  __shared__ float tile[32][33];
  int n0 = blockIdx.x * 32, k0 = blockIdx.y * 32;
  int tx = threadIdx.x & 31, ty = threadIdx.x >> 5;
#pragma unroll
  for (int i = 0; i < 4; i++)
    tile[ty + i * 8][tx] = W[(size_t)(k0 + ty + i * 8) * 1024 + n0 + tx];
  __syncthreads();
#pragma unroll
  for (int i = 0; i < 4; i++)
    out[(size_t)(n0 + ty + i * 8) * 1024 + k0 + tx] = (bf16)tile[tx][ty + i * 8];
}

// V [b][kv][s][d] -> Vt [b][kv][d][s], 64x64 LDS tiles
__global__ void trans_v_kernel(const bf16* __restrict__ Vb, bf16* __restrict__ Vt) {
  __shared__ bf16 t[64][65];
  int s0 = blockIdx.x * 64;
  size_t base = (size_t)blockIdx.y * 2048 * 64;
  int tx = threadIdx.x & 63, ty = threadIdx.x >> 6;
#pragma unroll
  for (int i = 0; i < 16; i++) {
    int row = ty * 16 + i;
    t[tx][row] = Vb[base + (size_t)(s0 + row) * 64 + tx];
  }
  __syncthreads();
  size_t obase = (size_t)blockIdx.y * 64 * 2048;
#pragma unroll
  for (int i = 0; i < 16; i++) {
    int d = ty * 16 + i;
    Vt[obase + (size_t)d * 2048 + s0 + tx] = t[d][tx];
  }
}

// ---------------- GEMM: C[M][N] = A[M][K] * Bt[N][K]^T, bf16 in, fp32 acc ----------------
template <bool OUT_BF16>
__global__ __launch_bounds__(256) void gemm_kernel(const bf16* __restrict__ A,
                                                   const bf16* __restrict__ Bt,
                                                   void* __restrict__ Cout,
                                                   int M, int N, int K) {
  __shared__ bf16 As[128 * 40];
  __shared__ bf16 Bs[128 * 40];
  const int tid = threadIdx.x;
  const int m0 = blockIdx.y * 128, n0 = blockIdx.x * 128;
  const int w = tid >> 6, lane = tid & 63;
  const int q = lane >> 4, r0 = lane & 15;
  const int wr2 = w >> 1, wc2 = w & 1;
  const int srow = tid >> 2;
  const int scol = (tid & 3) * 8;

  floatx4 acc[4][4];
#pragma unroll
  for (int i = 0; i < 4; i++)
#pragma unroll
    for (int j = 0; j < 4; j++) acc[i][j] = (floatx4){0.f, 0.f, 0.f, 0.f};

  for (int k0 = 0; k0 < K; k0 += 32) {
    __syncthreads();
#pragma unroll
    for (int i = 0; i < 2; i++) {
      int r = srow + i * 64;
      *(uint4*)&As[r * 40 + scol] = *(const uint4*)(A + (size_t)(m0 + r) * K + k0 + scol);
      *(uint4*)&Bs[r * 40 + scol] = *(const uint4*)(Bt + (size_t)(n0 + r) * K + k0 + scol);
    }
    __syncthreads();
    bf16x8 af[4], bfr[4];
#pragma unroll
    for (int mt = 0; mt < 4; mt++) af[mt] = *(const bf16x8*)&As[(wr2 * 64 + mt * 16 + r0) * 40 + q * 8];
#pragma unroll
    for (int nt = 0; nt < 4; nt++) bfr[nt] = *(const bf16x8*)&Bs[(wc2 * 64 + nt * 16 + r0) * 40 + q * 8];
#pragma unroll
    for (int mt = 0; mt < 4; mt++)
#pragma unroll
      for (int nt = 0; nt < 4; nt++)
        acc[mt][nt] = mfma16(af[mt], bfr[nt], acc[mt][nt]);
  }
#pragma unroll
  for (int mt = 0; mt < 4; mt++)
#pragma unroll
    for (int nt = 0; nt < 4; nt++)
#pragma unroll
      for (int r = 0; r < 4; r++) {
        int row = m0 + wr2 * 64 + mt * 16 + q * 4 + r;
        int col = n0 + wc2 * 64 + nt * 16 + r0;
        float v = acc[mt][nt][r];
        if (OUT_BF16) ((bf16*)Cout)[(size_t)row * N + col] = (bf16)v;
        else          ((float*)Cout)[(size_t)row * N + col] = v;
      }
}

// ---------------- postproc: gate+ve add, RoPE, RMS, layout for attention ----------------
__global__ void postproc_kernel(const bf16* __restrict__ qkv, const float* __restrict__ x,
                                const float* __restrict__ ve, const float* __restrict__ cosb,
                                const float* __restrict__ sinb, const float* __restrict__ wgate,
                                bf16* __restrict__ Qb, bf16* __restrict__ Kb, bf16* __restrict__ Vb) {
  int t = blockIdx.x;
  int b = t >> 11, s = t & 2047;
  int lane = threadIdx.x;

  // gate = 2*sigmoid(x[:,:128] @ Wgate)  (Wgate: [128][4] row-major)
  float g[4];
  const float* xrow = x + (size_t)t * 1024;
  float x0 = xrow[lane], x1 = xrow[64 + lane];
#pragma unroll
  for (int kv = 0; kv < 4; kv++)
    g[kv] = x0 * wgate[lane * 4 + kv] + x1 * wgate[(64 + lane) * 4 + kv];
#pragma unroll
  for (int kv = 0; kv < 4; kv++) {
    float v = g[kv];
    for (int m = 1; m < 64; m <<= 1) v += __shfl_xor(v, m, 64);
    g[kv] = 2.f / (1.f + __expf(-v));
  }

  int d = lane & 31;
  float c = cosb[s * 32 + d], sn = sinb[s * 32 + d];
  float sgn = (lane < 32) ? sn : -sn;
  const bf16* qrow = qkv + (size_t)t * 1536;

  // q heads: rope -> rms -> * (0.125*log2e) (score scale + exp2 conversion folded in)
  for (int h = 0; h < 16; h++) {
    float v = (float)qrow[h * 64 + lane];
    float p = __shfl_xor(v, 32, 64);
    float rv = v * c + p * sgn;
    float ss = rv * rv;
    for (int m = 1; m < 64; m <<= 1) ss += __shfl_xor(ss, m, 64);
    float outq = rv * rsqrtf(ss * (1.f / 64.f) + EPS) * QSCALE;
    Qb[(((size_t)b * 16 + h) * 2048 + s) * 64 + lane] = (bf16)outq;
  }
  // k heads + v (v gets gate*ve, no rope/rms; coalesced [s][d] layout)
  for (int kv = 0; kv < 4; kv++) {
    float v = (float)qrow[1024 + kv * 64 + lane];
    float p = __shfl_xor(v, 32, 64);
    float rv = v * c + p * sgn;
    float ss = rv * rv;
    for (int m = 1; m < 64; m <<= 1) ss += __shfl_xor(ss, m, 64);
    float outk = rv * rsqrtf(ss * (1.f / 64.f) + EPS);
    Kb[(((size_t)b * 4 + kv) * 2048 + s) * 64 + lane] = (bf16)outk;
    float vv = (float)qrow[1280 + kv * 64 + lane] + g[kv] * ve[(size_t)t * 256 + kv * 64 + lane];
    Vb[(((size_t)b * 4 + kv) * 2048 + s) * 64 + lane] = (bf16)vv;
  }
}

// ---------------- flash attention: fixed-shift softmax, prefetch-pipelined ----------------
__global__ __launch_bounds__(256) void attn_kernel(const bf16* __restrict__ Qb,
                                                   const bf16* __restrict__ Kb,
                                                   const bf16* __restrict__ Vt,
                                                   const int* __restrict__ wlp,
                                                   const int* __restrict__ wrp,
                                                   bf16* __restrict__ Yb) {
  __shared__ bf16 Ps[4 * 16 * 40];
  const int wl = wlp[0];
  const int wrc = min(wrp[0], 0);  // j<=i+wr && j<=i  ==>  j <= i+min(wr,0)
  const int blk = blockIdx.x;
  const int qc = 31 - (blk & 31);  // reversed: longest blocks (big q0) launch first
  const int bh = blk >> 5;
  const int b = bh >> 4, h = bh & 15, kvh = (bh & 15) >> 2;
  const int w = threadIdx.x >> 6, lane = threadIdx.x & 63;
  const int q = lane >> 4, r0 = lane & 15;
  const int q0 = qc * 64 + w * 16;

  const bf16* qbase = Qb + (((size_t)b * 16 + h) * 2048 + q0 + r0) * 64;
  bf16x8 aq0 = *(const bf16x8*)(qbase + q * 8);
  bf16x8 aq1 = *(const bf16x8*)(qbase + 32 + q * 8);

  floatx4 Oacc[4];
#pragma unroll
  for (int nt = 0; nt < 4; nt++) Oacc[nt] = (floatx4){0.f, 0.f, 0.f, 0.f};
  float lacc[4] = {0.f, 0.f, 0.f, 0.f};

  int jlo = max(0, q0 - wl) & ~31;
  int jhi = q0 + 15 + wrc;

  const bf16* kbase = Kb + ((size_t)b * 4 + kvh) * 2048 * 64;
  const bf16* vbase = Vt + ((size_t)b * 4 + kvh) * 64 * 2048;
  bf16* psw = Ps + w * 640;

  // prologue: load first tile's K and V fragments
  bf16x8 kf00 = *(const bf16x8*)(kbase + (size_t)(jlo + r0) * 64 + q * 8);
  bf16x8 kf01 = *(const bf16x8*)(kbase + (size_t)(jlo + r0) * 64 + 32 + q * 8);
  bf16x8 kf10 = *(const bf16x8*)(kbase + (size_t)(jlo + 16 + r0) * 64 + q * 8);
  bf16x8 kf11 = *(const bf16x8*)(kbase + (size_t)(jlo + 16 + r0) * 64 + 32 + q * 8);
  bf16x8 vf[4];
#pragma unroll
  for (int nt = 0; nt < 4; nt++)
    vf[nt] = *(const bf16x8*)(vbase + (size_t)(nt * 16 + r0) * 2048 + jlo + q * 8);

  for (int j0 = jlo; j0 <= jhi; j0 += 32) {
    floatx4 s0 = (floatx4){0.f, 0.f, 0.f, 0.f};
    floatx4 s1 = (floatx4){0.f, 0.f, 0.f, 0.f};
    s0 = mfma16(aq0, kf00, s0);
    s0 = mfma16(aq1, kf01, s0);
    s1 = mfma16(aq0, kf10, s1);
    s1 = mfma16(aq1, kf11, s1);

    // prefetch next tile (clamped re-load of current on last iter)
    int jn = (j0 + 32 <= jhi) ? j0 + 32 : j0;
    bf16x8 nk00 = *(const bf16x8*)(kbase + (size_t)(jn + r0) * 64 + q * 8);
    bf16x8 nk01 = *(const bf16x8*)(kbase + (size_t)(jn + r0) * 64 + 32 + q * 8);
    bf16x8 nk10 = *(const bf16x8*)(kbase + (size_t)(jn + 16 + r0) * 64 + q * 8);
    bf16x8 nk11 = *(const bf16x8*)(kbase + (size_t)(jn + 16 + r0) * 64 + 32 + q * 8);
    bf16x8 nv[4];
#pragma unroll
    for (int nt = 0; nt < 4; nt++)
      nv[nt] = *(const bf16x8*)(vbase + (size_t)(nt * 16 + r0) * 2048 + jn + q * 8);

    // fixed-shift softmax: p = exp2(s' - C), no running max, no rescale
    int ja = j0 + r0, jb = j0 + 16 + r0;
#pragma unroll
    for (int r = 0; r < 4; r++) {
      int i = q0 + q * 4 + r;
      bool va = (ja <= i + wrc) && (ja >= i - wl);
      bool vb = (jb <= i + wrc) && (jb >= i - wl);
      float ea = va ? exp2f(s0[r] - SHIFT_C) : 0.f;
      float eb = vb ? exp2f(s1[r] - SHIFT_C) : 0.f;
      lacc[r] += ea + eb;
      psw[(q * 4 + r) * 40 + r0] = (bf16)ea;
      psw[(q * 4 + r) * 40 + 16 + r0] = (bf16)eb;
    }
    asm volatile("s_waitcnt lgkmcnt(0)" ::: "memory");
    bf16x8 pa = *(const bf16x8*)(psw + r0 * 40 + q * 8);
#pragma unroll
    for (int nt = 0; nt < 4; nt++) Oacc[nt] = mfma16(pa, vf[nt], Oacc[nt]);

    kf00 = nk00; kf01 = nk01; kf10 = nk10; kf11 = nk11;
#pragma unroll
    for (int nt = 0; nt < 4; nt++) vf[nt] = nv[nt];
  }

  // single end-of-wave row-sum reduction (within each 16-lane group)
  float inv[4];
#pragma unroll
  for (int r = 0; r < 4; r++) {
    float l = lacc[r];
    l += __shfl_xor(l, 1, 64);
    l += __shfl_xor(l, 2, 64);
    l += __shfl_xor(l, 4, 64);
    l += __shfl_xor(l, 8, 64);
    inv[r] = 1.f / l;
  }
#pragma unroll
  for (int nt = 0; nt < 4; nt++)
#pragma unroll
    for (int r = 0; r < 4; r++) {
      int i = q0 + q * 4 + r;
      Yb[((size_t)b * 2048 + i) * 1024 + h * 64 + nt * 16 + r0] = (bf16)(Oacc[nt][r] * inv[r]);
    }
}

// ---------------- launch ----------------
extern "C" void kernel_launch(void* const* d_in, const int* in_sizes, int n_in,
                              void* d_out, int out_size, void* d_ws, size_t ws_size,
                              hipStream_t stream) {
  const float* x     = (const float*)d_in[0];
  const float* ve    = (const float*)d_in[1];
  const float* cosb  = (const float*)d_in[2];
  const float* sinb  = (const float*)d_in[3];
  const float* Wq    = (const float*)d_in[4];
  const float* Wk    = (const float*)d_in[5];
  const float* Wv    = (const float*)d_in[6];
  const float* Wproj = (const float*)d_in[7];
  const float* Wgate = (const float*)d_in[8];
  const int* wl      = (const int*)d_in[9];
  const int* wr      = (const int*)d_in[10];

  char* ws = (char*)d_ws;
  bf16* Xb      = (bf16*)(ws);                 //  8,388,608 B: x bf16 [4096][1024]
  bf16* Wqkv_t  = (bf16*)(ws + 8388608);       //  3,145,728 B: [1536][1024]
  bf16* Wproj_t = (bf16*)(ws + 11534336);      //  2,097,152 B: [1024][1024]
  bf16* qkvb    = (bf16*)(ws + 13631488);      // 12,582,912 B: [4096][1536]
  bf16* Qb      = (bf16*)(ws + 26214400);      //  8,388,608 B: [2][16][2048][64]
  bf16* Kb      = (bf16*)(ws + 34603008);      //  2,097,152 B: [2][4][2048][64]
  bf16* Vt      = (bf16*)(ws + 36700160);      //  2,097,152 B: [2][4][64][2048]
  bf16* Yb      = (bf16*)(ws + 38797312);      //  8,388,608 B: [4096][1024]  (total 47,185,920)
  bf16* Vb      = Yb;                          //  2 MB staging inside Yb (dead before attn writes Yb)

  cast_x_kernel<<<4096, 256, 0, stream>>>(x, Xb);
  pack_wqkv_kernel<<<dim3(48, 32), 256, 0, stream>>>(Wq, Wk, Wv, Wqkv_t);
  trans_wproj_kernel<<<dim3(32, 32), 256, 0, stream>>>(Wproj, Wproj_t);
  gemm_kernel<true><<<dim3(12, 32), 256, 0, stream>>>(Xb, Wqkv_t, qkvb, 4096, 1536, 1024);
  postproc_kernel<<<4096, 64, 0, stream>>>(qkvb, x, ve, cosb, sinb, Wgate, Qb, Kb, Vb);
  trans_v_kernel<<<dim3(32, 8), 256, 0, stream>>>(Vb, Vt);
  attn_kernel<<<1024, 256, 0, stream>>>(Qb, Kb, Vt, wl, wr, Yb);
  gemm_kernel<false><<<dim3(8, 32), 256, 0, stream>>>(Yb, Wproj_t, d_out, 4096, 1024, 1024);
}